// Round 5
// baseline (1052.135 us; speedup 1.0000x reference)
//
#include <hip/hip_runtime.h>
#include <stdint.h>

#define BATCH 8
#define CIN   128
#define HH    192
#define WW    192
#define HW    (HH*WW)       // 36864
#define PXB   576           // (HW/64) pixel-tiles per batch
#define CH    2             // channels per corr block

typedef _Float16 half_t;
typedef _Float16 f16x8 __attribute__((ext_vector_type(8)));
typedef _Float16 f16x2 __attribute__((ext_vector_type(2)));
typedef float    f32x4 __attribute__((ext_vector_type(4)));
typedef unsigned int u32;

// packed f16 dot2 with f32 accumulate (v_dot2_f32_f16)
__device__ __forceinline__ float DOT2(u32 a, u32 b, float c) {
#if __has_builtin(__builtin_amdgcn_fdot2)
    return __builtin_amdgcn_fdot2(__builtin_bit_cast(f16x2, a),
                                  __builtin_bit_cast(f16x2, b), c, false);
#else
    f16x2 av = __builtin_bit_cast(f16x2, a), bv = __builtin_bit_cast(f16x2, b);
    return c + (float)av[0] * (float)bv[0] + (float)av[1] * (float)bv[1];
#endif
}

// ---------------------------------------------------------------------------
// Fused LayerNorm(channel) + 1x1 conv (GEMM) via MFMA f16.  (unchanged)
// ---------------------------------------------------------------------------
template<int OC>
__global__ __launch_bounds__(256)
void ln_gemm_kernel(const float* __restrict__ x,
                    const float* __restrict__ lnw, const float* __restrict__ lnb,
                    const float* __restrict__ w,   const float* __restrict__ wb,
                    half_t* __restrict__ out)
{
    __shared__ __attribute__((aligned(16))) half_t As[64][136];
    __shared__ __attribute__((aligned(16))) half_t Wsh[64][136];
    __shared__ float  redA[4][64];
    __shared__ float  redB[4][64];
    __shared__ float  mu_s[64], rs_s[64];

    const int tid = threadIdx.x;
    const int px  = tid & 63;
    const int g   = tid >> 6;
    const int l   = tid & 63;
    const int wv  = tid >> 6;

    const long p0  = (long)blockIdx.x * 64;
    const int  b   = (int)(p0 / HW);
    const int  hw0 = (int)(p0 - (long)b * HW);

    const float* xb = x + (size_t)b * CIN * HW + hw0 + px;
    float vals[32];
    float s1 = 0.f, s2 = 0.f;
#pragma unroll
    for (int j = 0; j < 32; ++j) {
        float v = xb[(size_t)(g * 32 + j) * HW];
        vals[j] = v; s1 += v; s2 += v * v;
    }
    redA[g][px] = s1; redB[g][px] = s2;
    __syncthreads();
    if (tid < 64) {
        float su = redA[0][tid] + redA[1][tid] + redA[2][tid] + redA[3][tid];
        float sq = redB[0][tid] + redB[1][tid] + redB[2][tid] + redB[3][tid];
        float mu  = su * (1.f / 128.f);
        float var = sq * (1.f / 128.f) - mu * mu;
        mu_s[tid] = mu;
        rs_s[tid] = rsqrtf(var + 1e-5f);
    }
    __syncthreads();
    {
        float mu = mu_s[px], rs = rs_s[px];
#pragma unroll
        for (int j = 0; j < 32; ++j) {
            int c = g * 32 + j;
            float a = (vals[j] - mu) * rs * lnw[c] + lnb[c];
            As[px][c] = (half_t)a;
        }
    }

    for (int nc = 0; nc < OC / 64; ++nc) {
        const int n0 = nc * 64;
#pragma unroll
        for (int i = 0; i < 8; ++i) {
            int f  = i * 256 + tid;
            int n  = f >> 5;
            int kq = (f & 31) << 2;
            const float4 wvv = *(const float4*)&w[(size_t)(n0 + n) * CIN + kq];
            Wsh[n][kq]     = (half_t)wvv.x;
            Wsh[n][kq + 1] = (half_t)wvv.y;
            Wsh[n][kq + 2] = (half_t)wvv.z;
            Wsh[n][kq + 3] = (half_t)wvv.w;
        }
        __syncthreads();

        f16x8 af[4];
#pragma unroll
        for (int kt = 0; kt < 4; ++kt)
            af[kt] = *(const f16x8*)&Wsh[wv * 16 + (l & 15)][kt * 32 + (l >> 4) * 8];

#pragma unroll
        for (int pt = 0; pt < 4; ++pt) {
            f32x4 acc = {0.f, 0.f, 0.f, 0.f};
#pragma unroll
            for (int kt = 0; kt < 4; ++kt) {
                f16x8 bfv = *(const f16x8*)&As[pt * 16 + (l & 15)][kt * 32 + (l >> 4) * 8];
                acc = __builtin_amdgcn_mfma_f32_16x16x32_f16(af[kt], bfv, acc, 0, 0, 0);
            }
#pragma unroll
            for (int r = 0; r < 4; ++r) {
                int n  = n0 + wv * 16 + (l >> 4) * 4 + r;
                int po = pt * 16 + (l & 15);
                float v = acc[r] + wb[n];
                out[((size_t)b * OC + n) * HW + hw0 + po] = (half_t)v;
            }
        }
        __syncthreads();
    }
}

// ---------------------------------------------------------------------------
// Strip-based fused dwconv(q,k,v) + per-patch 8x8 circular conv, v2.
// Block = 384 threads = (lb, patch-row ph, CH=2 channels).
//   stage A: coalesced f16x8 strip loads (10 rows x 192 cols + halo), 6 arrays
//   stage B: dwconv3x3 (exactly 3 units/thread):
//              q -> qd[2][8][192]; k -> krev2 (reversed-circular, doubled);
//              v -> global vd
//   stage C: circular conv per (c,pw,u) (1 unit/thread) via v_dot2_f32_f16:
//              acc[v] = sum_s sum_t q[s][t] * krev2[(u-s)&7][t + 8 - v]
// LDS = 24960 + 6144 + 12544 = 43.6 KB -> 3 blocks/CU (18 waves).
// ---------------------------------------------------------------------------
__global__ __launch_bounds__(384)
void corr_strip_kernel(const half_t* __restrict__ q1, const half_t* __restrict__ kv1,
                       const float* __restrict__ qw, const float* __restrict__ qb,
                       const float* __restrict__ kw, const float* __restrict__ kb,
                       half_t* __restrict__ corr, half_t* __restrict__ vd)
{
    __shared__ __attribute__((aligned(16))) half_t raw[6][10][208];
    __shared__ __attribute__((aligned(16))) half_t qd[2][8][192];
    __shared__ __attribute__((aligned(16))) half_t krev2[2][8][392]; // 24*16 + 8 pad

    const int bid = blockIdx.x;
    const int cg  = bid & 127;          // 128 channel-groups of CH=2
    const int ph  = (bid >> 7) % 24;
    const int lb  = (bid >> 7) / 24;
    const int c0  = cg * CH;
    const int tid = threadIdx.x;

    // ---- zero the column-halo slots (cols 0..7 and 200..207) ----
    if (tid < 120) {
        int side = tid & 1;
        int row  = (tid >> 1) % 10;
        int a    = tid / 20;            // 0..5
        f16x8 z = {};
        *(f16x8*)&raw[a][row][side ? 200 : 0] = z;
    }

    // ---- stage A: coalesced strip loads (rows ph*8-1 .. ph*8+8) ----
#pragma unroll
    for (int i = 0; i < 4; ++i) {
        int idx = tid + 384 * i;        // 1440 vector-loads total
        if (idx >= 1440) break;
        int vec = idx % 24;             // col group (8 cols)
        int row = (idx / 24) % 10;
        int a   = idx / 240;            // 0..5
        int ch  = a & 1;
        int gh  = ph * 8 - 1 + row;
        f16x8 v = {};
        if (gh >= 0 && gh < HH) {
            const half_t* src;
            if (a < 2)      src = q1  + ((size_t)lb * 256 + c0 + ch) * HW;
            else if (a < 4) src = kv1 + ((size_t)lb * 512 + c0 + ch) * HW;
            else            src = kv1 + ((size_t)lb * 512 + 256 + c0 + ch) * HW;
            v = *(const f16x8*)&src[(size_t)gh * WW + vec * 8];
        }
        *(f16x8*)&raw[a][row][8 + vec * 8] = v;
    }
    __syncthreads();

    // ---- stage B: depthwise 3x3; 1152 units = (a, u, xg), 3 exact iters ----
#pragma unroll
    for (int i = 0; i < 3; ++i) {
        int unit = tid + 384 * i;
        int xg = unit % 24;
        int u  = (unit / 24) % 8;
        int a  = unit / 192;            // i=0: a=0,1 (q); i=1: a=2,3 (k); i=2: a=4,5 (v)
        int ch = a & 1;
        const half_t (*rw)[208] = raw[a];
        const float* wt;
        float bias;
        if (a < 2)      { wt = qw + (size_t)(c0 + ch) * 9;       bias = qb[c0 + ch]; }
        else if (a < 4) { wt = kw + (size_t)(c0 + ch) * 9;       bias = kb[c0 + ch]; }
        else            { wt = kw + (size_t)(256 + c0 + ch) * 9; bias = kb[256 + c0 + ch]; }
        int x0 = xg * 8;
        float r0[10], r1[10], r2[10];
#pragma unroll
        for (int j = 0; j < 10; ++j) {
            r0[j] = (float)rw[u + 0][7 + x0 + j];
            r1[j] = (float)rw[u + 1][7 + x0 + j];
            r2[j] = (float)rw[u + 2][7 + x0 + j];
        }
        float acc[8];
#pragma unroll
        for (int xx = 0; xx < 8; ++xx) acc[xx] = bias;
#pragma unroll
        for (int dx = 0; dx < 3; ++dx) {
            float w0 = wt[dx], w1 = wt[3 + dx], w2 = wt[6 + dx];
#pragma unroll
            for (int xx = 0; xx < 8; ++xx) {
                acc[xx] += r0[xx + dx] * w0 + r1[xx + dx] * w1 + r2[xx + dx] * w2;
            }
        }
        if (a < 2) {
            f16x8 o;
#pragma unroll
            for (int xx = 0; xx < 8; ++xx) o[xx] = (half_t)acc[xx];
            *(f16x8*)&qd[ch][u][x0] = o;
        } else if (a < 4) {
            // reversed-circular order, stored doubled: krev[j] = k[(8-j)&7]
            f16x8 o;
            o[0] = (half_t)acc[0];
#pragma unroll
            for (int j = 1; j < 8; ++j) o[j] = (half_t)acc[8 - j];
            *(f16x8*)&krev2[ch][u][xg * 16]     = o;
            *(f16x8*)&krev2[ch][u][xg * 16 + 8] = o;
        } else {
            f16x8 o;
#pragma unroll
            for (int xx = 0; xx < 8; ++xx) o[xx] = (half_t)acc[xx];
            *(f16x8*)&vd[((size_t)lb * 256 + c0 + ch) * HW + (size_t)(ph * 8 + u) * WW + x0] = o;
        }
    }
    __syncthreads();

    // ---- stage C: per-patch circular conv via dot2, 1 unit/thread ----
    {
        int c   = tid / 192;
        int rem = tid % 192;
        int pw  = rem >> 3;
        int u   = rem & 7;
        float acc[8];
#pragma unroll
        for (int v = 0; v < 8; ++v) acc[v] = 0.f;
#pragma unroll
        for (int s = 0; s < 8; ++s) {
            int r = (u - s) & 7;
            uint4 q4 = *(const uint4*)&qd[c][s][pw * 8];
            uint4 ka = *(const uint4*)&krev2[c][r][pw * 16];
            uint4 kb4 = *(const uint4*)&krev2[c][r][pw * 16 + 8];
            u32 Q[4] = {q4.x, q4.y, q4.z, q4.w};
            u32 K[8] = {ka.x, ka.y, ka.z, ka.w, kb4.x, kb4.y, kb4.z, kb4.w};
            u32 S[7];
#pragma unroll
            for (int m = 0; m < 7; ++m) S[m] = (K[m] >> 16) | (K[m + 1] << 16);
#pragma unroll
            for (int v = 0; v < 8; ++v) {
                const int o = 8 - v;
#pragma unroll
                for (int tt = 0; tt < 4; ++tt) {
                    const int h = 2 * tt + o;
                    u32 pr = (h & 1) ? S[(h - 1) >> 1] : K[h >> 1];
                    acc[v] = DOT2(Q[tt], pr, acc[v]);
                }
            }
        }
        f16x8 ov;
#pragma unroll
        for (int v = 0; v < 8; ++v) ov[v] = (half_t)acc[v];
        *(f16x8*)&corr[((size_t)lb * 256 + c0 + c) * HW + (size_t)(ph * 8 + u) * WW + pw * 8] = ov;
    }
}

// ---------------------------------------------------------------------------
// Fused LN(corr)*vd + 1x1 proj GEMM (K=256 split in 2, N=128) -> f32 out.
// (unchanged)
// ---------------------------------------------------------------------------
__global__ __launch_bounds__(256)
void proj_kernel(const half_t* __restrict__ corr, const half_t* __restrict__ vd,
                 const float* __restrict__ lnw, const float* __restrict__ lnb,
                 const float* __restrict__ w,   const float* __restrict__ wb,
                 float* __restrict__ out)
{
    __shared__ __attribute__((aligned(16))) half_t As[64][136];
    __shared__ __attribute__((aligned(16))) half_t Wsh[128][136];
    __shared__ float  redA[4][64];
    __shared__ float  redB[4][64];
    __shared__ float  mu_s[64], rs_s[64];

    const int tid = threadIdx.x;
    const int px  = tid & 63;
    const int g   = tid >> 6;
    const int l   = tid & 63;
    const int wv  = tid >> 6;

    const long p0  = (long)blockIdx.x * 64;
    const int  lb  = (int)(p0 / HW);
    const int  hw0 = (int)(p0 - (long)lb * HW);

    const half_t* cb = corr + (size_t)lb * 256 * HW + hw0 + px;
    const half_t* vb = vd   + (size_t)lb * 256 * HW + hw0 + px;

    float s1 = 0.f, s2 = 0.f;
#pragma unroll 8
    for (int j = 0; j < 64; ++j) {
        float cv = (float)cb[(size_t)(g * 64 + j) * HW];
        s1 += cv; s2 += cv * cv;
    }
    redA[g][px] = s1; redB[g][px] = s2;
    __syncthreads();
    if (tid < 64) {
        float su = redA[0][tid] + redA[1][tid] + redA[2][tid] + redA[3][tid];
        float sq = redB[0][tid] + redB[1][tid] + redB[2][tid] + redB[3][tid];
        float mu  = su * (1.f / 256.f);
        float var = sq * (1.f / 256.f) - mu * mu;
        mu_s[tid] = mu;
        rs_s[tid] = rsqrtf(var + 1e-5f);
    }
    __syncthreads();
    const float mu = mu_s[px], rs = rs_s[px];

    f32x4 acc[2][4];
#pragma unroll
    for (int nt = 0; nt < 2; ++nt)
#pragma unroll
        for (int pt = 0; pt < 4; ++pt) acc[nt][pt] = {0.f, 0.f, 0.f, 0.f};

    for (int kc = 0; kc < 2; ++kc) {
#pragma unroll 4
        for (int j = 0; j < 32; ++j) {
            int cl = g * 32 + j;
            int c  = kc * 128 + cl;
            float cv = (float)cb[(size_t)c * HW];
            float vv = (float)vb[(size_t)c * HW];
            As[px][cl] = (half_t)(((cv - mu) * rs * lnw[c] + lnb[c]) * vv);
        }
#pragma unroll
        for (int i = 0; i < 16; ++i) {
            int f  = i * 256 + tid;
            int n  = f >> 5;
            int kq = (f & 31) << 2;
            const float4 wvv = *(const float4*)&w[(size_t)n * 256 + kc * 128 + kq];
            Wsh[n][kq]     = (half_t)wvv.x;
            Wsh[n][kq + 1] = (half_t)wvv.y;
            Wsh[n][kq + 2] = (half_t)wvv.z;
            Wsh[n][kq + 3] = (half_t)wvv.w;
        }
        __syncthreads();

#pragma unroll
        for (int nt = 0; nt < 2; ++nt) {
            f16x8 af[4];
#pragma unroll
            for (int kt = 0; kt < 4; ++kt)
                af[kt] = *(const f16x8*)&Wsh[wv * 32 + nt * 16 + (l & 15)][kt * 32 + (l >> 4) * 8];
#pragma unroll
            for (int pt = 0; pt < 4; ++pt) {
#pragma unroll
                for (int kt = 0; kt < 4; ++kt) {
                    f16x8 bfv = *(const f16x8*)&As[pt * 16 + (l & 15)][kt * 32 + (l >> 4) * 8];
                    acc[nt][pt] = __builtin_amdgcn_mfma_f32_16x16x32_f16(af[kt], bfv, acc[nt][pt], 0, 0, 0);
                }
            }
        }
        __syncthreads();
    }

#pragma unroll
    for (int nt = 0; nt < 2; ++nt)
#pragma unroll
        for (int pt = 0; pt < 4; ++pt)
#pragma unroll
            for (int r = 0; r < 4; ++r) {
                int n  = wv * 32 + nt * 16 + (l >> 4) * 4 + r;
                int po = pt * 16 + (l & 15);
                out[((size_t)lb * 128 + n) * HW + hw0 + po] = acc[nt][pt][r] + wb[n];
            }
}

// ---------------------------------------------------------------------------
extern "C" void kernel_launch(void* const* d_in, const int* in_sizes, int n_in,
                              void* d_out, int out_size, void* d_ws, size_t ws_size,
                              hipStream_t stream)
{
    const float* x        = (const float*)d_in[0];
    const float* evt      = (const float*)d_in[1];
    const float* ln_img_w = (const float*)d_in[2];
    const float* ln_img_b = (const float*)d_in[3];
    const float* ln_evt_w = (const float*)d_in[4];
    const float* ln_evt_b = (const float*)d_in[5];
    const float* q_w      = (const float*)d_in[6];
    const float* q_b      = (const float*)d_in[7];
    const float* q_dw_w   = (const float*)d_in[8];
    const float* q_dw_b   = (const float*)d_in[9];
    const float* kv_w     = (const float*)d_in[10];
    const float* kv_b     = (const float*)d_in[11];
    const float* kv_dw_w  = (const float*)d_in[12];
    const float* kv_dw_b  = (const float*)d_in[13];
    const float* ln_corr_w= (const float*)d_in[14];
    const float* ln_corr_b= (const float*)d_in[15];
    const float* proj_w   = (const float*)d_in[16];
    const float* proj_b   = (const float*)d_in[17];
    float* out = (float*)d_out;

    const size_t per_b = (size_t)(256 + 512 + 256 + 256) * HW * sizeof(half_t); // 94.4 MB
    int PB = 1;
    if      (ws_size >= 8 * per_b) PB = 8;
    else if (ws_size >= 4 * per_b) PB = 4;
    else if (ws_size >= 2 * per_b) PB = 2;

    half_t* q1   = (half_t*)d_ws;
    half_t* kv1  = q1  + (size_t)PB * 256 * HW;
    half_t* vd   = kv1 + (size_t)PB * 512 * HW;
    half_t* corr = vd  + (size_t)PB * 256 * HW;

    dim3 blk(256);
    dim3 blk384(384);
    for (int b0 = 0; b0 < BATCH; b0 += PB) {
        int nb = PB;
        ln_gemm_kernel<256><<<nb * PXB, blk, 0, stream>>>(
            x + (size_t)b0 * CIN * HW, ln_img_w, ln_img_b, q_w, q_b, q1);
        ln_gemm_kernel<512><<<nb * PXB, blk, 0, stream>>>(
            evt + (size_t)b0 * CIN * HW, ln_evt_w, ln_evt_b, kv_w, kv_b, kv1);
        corr_strip_kernel<<<nb * 24 * 128, blk384, 0, stream>>>(
            q1, kv1, q_dw_w, q_dw_b, kv_dw_w, kv_dw_b, corr, vd);
        proj_kernel<<<nb * PXB, blk, 0, stream>>>(
            corr, vd, ln_corr_w, ln_corr_b, proj_w, proj_b,
            out + (size_t)b0 * 128 * HW);
    }
}

// Round 6
// 820.594 us; speedup vs baseline: 1.2822x; 1.2822x over previous
//
#include <hip/hip_runtime.h>
#include <stdint.h>

#define BATCH 8
#define CIN   128
#define HH    192
#define WW    192
#define HW    (HH*WW)       // 36864
#define PXB   576           // (HW/64) pixel-tiles per batch
#define CH    2             // channels per corr block

typedef _Float16 half_t;
typedef _Float16 f16x8 __attribute__((ext_vector_type(8)));
typedef _Float16 f16x4 __attribute__((ext_vector_type(4)));
typedef _Float16 f16x2 __attribute__((ext_vector_type(2)));
typedef float    f32x4 __attribute__((ext_vector_type(4)));
typedef unsigned int u32;

// packed f16 dot2 with f32 accumulate (v_dot2_f32_f16)
__device__ __forceinline__ float DOT2(u32 a, u32 b, float c) {
#if __has_builtin(__builtin_amdgcn_fdot2)
    return __builtin_amdgcn_fdot2(__builtin_bit_cast(f16x2, a),
                                  __builtin_bit_cast(f16x2, b), c, false);
#else
    f16x2 av = __builtin_bit_cast(f16x2, a), bv = __builtin_bit_cast(f16x2, b);
    return c + (float)av[0] * (float)bv[0] + (float)av[1] * (float)bv[1];
#endif
}

// ---------------------------------------------------------------------------
// One-shot weight f32 -> f16 conversion into workspace.
//   [0      .. 32768)  q_w   (256x128)
//   [32768  .. 98304)  kv_w  (512x128)
//   [98304  .. 131072) proj_w(128x256)
// ---------------------------------------------------------------------------
__global__ __launch_bounds__(256)
void wcvt_kernel(const float* __restrict__ qw, const float* __restrict__ kvw,
                 const float* __restrict__ pw, half_t* __restrict__ out)
{
    int q = blockIdx.x * 256 + threadIdx.x;      // float4 index, 32768 total
    if (q >= 32768) return;
    int idx = q * 4;
    const float* src;
    int off;
    if (idx < 32768)      { src = qw;  off = idx; }
    else if (idx < 98304) { src = kvw; off = idx - 32768; }
    else                  { src = pw;  off = idx - 98304; }
    float4 v = *(const float4*)&src[off];
    f16x4 o = { (half_t)v.x, (half_t)v.y, (half_t)v.z, (half_t)v.w };
    *(f16x4*)&out[idx] = o;
}

// ---------------------------------------------------------------------------
// Fused LayerNorm(channel) + 1x1 conv (GEMM) via MFMA f16.
// Weights pre-converted to f16 (wf16).
// ---------------------------------------------------------------------------
template<int OC>
__global__ __launch_bounds__(256)
void ln_gemm_kernel(const float* __restrict__ x,
                    const float* __restrict__ lnw, const float* __restrict__ lnb,
                    const half_t* __restrict__ wf16, const float* __restrict__ wb,
                    half_t* __restrict__ out)
{
    __shared__ __attribute__((aligned(16))) half_t As[64][136];
    __shared__ __attribute__((aligned(16))) half_t Wsh[64][136];
    __shared__ float  redA[4][64];
    __shared__ float  redB[4][64];
    __shared__ float  mu_s[64], rs_s[64];

    const int tid = threadIdx.x;
    const int px  = tid & 63;
    const int g   = tid >> 6;
    const int l   = tid & 63;
    const int wv  = tid >> 6;

    const long p0  = (long)blockIdx.x * 64;
    const int  b   = (int)(p0 / HW);
    const int  hw0 = (int)(p0 - (long)b * HW);

    const float* xb = x + (size_t)b * CIN * HW + hw0 + px;
    float vals[32];
    float s1 = 0.f, s2 = 0.f;
#pragma unroll
    for (int j = 0; j < 32; ++j) {
        float v = xb[(size_t)(g * 32 + j) * HW];
        vals[j] = v; s1 += v; s2 += v * v;
    }
    redA[g][px] = s1; redB[g][px] = s2;
    __syncthreads();
    if (tid < 64) {
        float su = redA[0][tid] + redA[1][tid] + redA[2][tid] + redA[3][tid];
        float sq = redB[0][tid] + redB[1][tid] + redB[2][tid] + redB[3][tid];
        float mu  = su * (1.f / 128.f);
        float var = sq * (1.f / 128.f) - mu * mu;
        mu_s[tid] = mu;
        rs_s[tid] = rsqrtf(var + 1e-5f);
    }
    __syncthreads();
    {
        float mu = mu_s[px], rs = rs_s[px];
#pragma unroll
        for (int j = 0; j < 32; ++j) {
            int c = g * 32 + j;
            float a = (vals[j] - mu) * rs * lnw[c] + lnb[c];
            As[px][c] = (half_t)a;
        }
    }

    for (int nc = 0; nc < OC / 64; ++nc) {
        const int n0 = nc * 64;
        // stage weights 64 x 128 f16: 1024 f16x8 loads, 4/thread
#pragma unroll
        for (int i = 0; i < 4; ++i) {
            int f  = i * 256 + tid;
            int n  = f >> 4;
            int x0 = (f & 15) * 8;
            *(f16x8*)&Wsh[n][x0] = *(const f16x8*)&wf16[(size_t)(n0 + n) * CIN + x0];
        }
        __syncthreads();

        f16x8 af[4];
#pragma unroll
        for (int kt = 0; kt < 4; ++kt)
            af[kt] = *(const f16x8*)&Wsh[wv * 16 + (l & 15)][kt * 32 + (l >> 4) * 8];

#pragma unroll
        for (int pt = 0; pt < 4; ++pt) {
            f32x4 acc = {0.f, 0.f, 0.f, 0.f};
#pragma unroll
            for (int kt = 0; kt < 4; ++kt) {
                f16x8 bfv = *(const f16x8*)&As[pt * 16 + (l & 15)][kt * 32 + (l >> 4) * 8];
                acc = __builtin_amdgcn_mfma_f32_16x16x32_f16(af[kt], bfv, acc, 0, 0, 0);
            }
#pragma unroll
            for (int r = 0; r < 4; ++r) {
                int n  = n0 + wv * 16 + (l >> 4) * 4 + r;
                int po = pt * 16 + (l & 15);
                float v = acc[r] + wb[n];
                out[((size_t)b * OC + n) * HW + hw0 + po] = (half_t)v;
            }
        }
        __syncthreads();
    }
}

// ---------------------------------------------------------------------------
// Strip-based fused dwconv(q,k,v) + per-patch 8x8 circular conv, v3.
// Round-4 skeleton (256 threads, ~37.5 KB LDS -> 4 blocks/CU) with dot2
// stage C: k stored reversed (single), odd windows via 4 alignbits.
// ---------------------------------------------------------------------------
__global__ __launch_bounds__(256)
void corr_strip_kernel(const half_t* __restrict__ q1, const half_t* __restrict__ kv1,
                       const float* __restrict__ qw, const float* __restrict__ qb,
                       const float* __restrict__ kw, const float* __restrict__ kb,
                       half_t* __restrict__ corr, half_t* __restrict__ vd)
{
    __shared__ __attribute__((aligned(16))) half_t raw[6][10][208];
    __shared__ __attribute__((aligned(16))) half_t qd[2][8][192];
    __shared__ __attribute__((aligned(16))) half_t krev[2][8][200]; // stride 200: rows 4 banks apart

    const int bid = blockIdx.x;
    const int cg  = bid & 127;          // 128 channel-groups of CH=2
    const int ph  = (bid >> 7) % 24;
    const int lb  = (bid >> 7) / 24;
    const int c0  = cg * CH;
    const int tid = threadIdx.x;

    // ---- zero the column-halo slots (cols 0..7 and 200..207) ----
    if (tid < 120) {
        int side = tid & 1;
        int row  = (tid >> 1) % 10;
        int a    = tid / 20;            // 0..5
        f16x8 z = {};
        *(f16x8*)&raw[a][row][side ? 200 : 0] = z;
    }

    // ---- stage A: coalesced strip loads (rows ph*8-1 .. ph*8+8) ----
    for (int i = 0; i < 6; ++i) {
        int idx = tid + 256 * i;        // 1440 vector-loads total
        if (idx >= 1440) break;
        int vec = idx % 24;             // col group (8 cols)
        int row = (idx / 24) % 10;
        int a   = idx / 240;            // 0..5
        int ch  = a & 1;
        int gh  = ph * 8 - 1 + row;
        f16x8 v = {};
        if (gh >= 0 && gh < HH) {
            const half_t* src;
            if (a < 2)      src = q1  + ((size_t)lb * 256 + c0 + ch) * HW;
            else if (a < 4) src = kv1 + ((size_t)lb * 512 + c0 + ch) * HW;
            else            src = kv1 + ((size_t)lb * 512 + 256 + c0 + ch) * HW;
            v = *(const f16x8*)&src[(size_t)gh * WW + vec * 8];
        }
        *(f16x8*)&raw[a][row][8 + vec * 8] = v;
    }
    __syncthreads();

    // ---- stage B: depthwise 3x3; 1152 units = (a, u, xg) ----
    for (int i = 0; i < 5; ++i) {
        int unit = tid + 256 * i;
        if (unit >= 1152) break;
        int xg = unit % 24;
        int u  = (unit / 24) % 8;
        int a  = unit / 192;            // 0..5
        int ch = a & 1;
        const half_t (*rw)[208] = raw[a];
        const float* wt;
        float bias;
        if (a < 2)      { wt = qw + (size_t)(c0 + ch) * 9;       bias = qb[c0 + ch]; }
        else if (a < 4) { wt = kw + (size_t)(c0 + ch) * 9;       bias = kb[c0 + ch]; }
        else            { wt = kw + (size_t)(256 + c0 + ch) * 9; bias = kb[256 + c0 + ch]; }
        int x0 = xg * 8;
        float r0[10], r1[10], r2[10];
#pragma unroll
        for (int j = 0; j < 10; ++j) {
            r0[j] = (float)rw[u + 0][7 + x0 + j];
            r1[j] = (float)rw[u + 1][7 + x0 + j];
            r2[j] = (float)rw[u + 2][7 + x0 + j];
        }
        float acc[8];
#pragma unroll
        for (int xx = 0; xx < 8; ++xx) acc[xx] = bias;
#pragma unroll
        for (int dx = 0; dx < 3; ++dx) {
            float w0 = wt[dx], w1 = wt[3 + dx], w2 = wt[6 + dx];
#pragma unroll
            for (int xx = 0; xx < 8; ++xx) {
                acc[xx] += r0[xx + dx] * w0 + r1[xx + dx] * w1 + r2[xx + dx] * w2;
            }
        }
        if (a < 2) {
            f16x8 o;
#pragma unroll
            for (int xx = 0; xx < 8; ++xx) o[xx] = (half_t)acc[xx];
            *(f16x8*)&qd[ch][u][x0] = o;
        } else if (a < 4) {
            // reversed-circular order: krev[j] = k[(8-j)&7]
            f16x8 o;
            o[0] = (half_t)acc[0];
#pragma unroll
            for (int j = 1; j < 8; ++j) o[j] = (half_t)acc[8 - j];
            *(f16x8*)&krev[ch][u][xg * 8] = o;
        } else {
            f16x8 o;
#pragma unroll
            for (int xx = 0; xx < 8; ++xx) o[xx] = (half_t)acc[xx];
            *(f16x8*)&vd[((size_t)lb * 256 + c0 + ch) * HW + (size_t)(ph * 8 + u) * WW + x0] = o;
        }
    }
    __syncthreads();

    // ---- stage C: circular conv via dot2 + register-circular windows ----
    // acc[v] = sum_s sum_t q[s][t] * krev[(u-s)&7][(8-v+t) mod 8]
    for (int i = 0; i < 2; ++i) {
        int unit = tid + 256 * i;       // 384 units: (c, pw, u)
        if (unit >= 384) break;
        int c   = unit / 192;
        int rem = unit % 192;
        int pw  = rem >> 3;
        int u   = rem & 7;
        float acc[8];
#pragma unroll
        for (int v = 0; v < 8; ++v) acc[v] = 0.f;
#pragma unroll
        for (int s = 0; s < 8; ++s) {
            int r = (u - s) & 7;
            uint4 q4 = *(const uint4*)&qd[c][s][pw * 8];
            uint4 k4 = *(const uint4*)&krev[c][r][pw * 8];
            u32 Q[4] = {q4.x, q4.y, q4.z, q4.w};
            u32 K[4] = {k4.x, k4.y, k4.z, k4.w};
            u32 S[4];
#pragma unroll
            for (int m = 0; m < 4; ++m) S[m] = (K[m] >> 16) | (K[(m + 1) & 3] << 16);
#pragma unroll
            for (int v = 0; v < 8; ++v) {
                const int o = 8 - v;    // window offset 1..8 (circular)
#pragma unroll
                for (int tt = 0; tt < 4; ++tt) {
                    u32 pr = (o & 1) ? S[(((o - 1) >> 1) + tt) & 3]
                                     : K[((o >> 1) + tt) & 3];
                    acc[v] = DOT2(Q[tt], pr, acc[v]);
                }
            }
        }
        f16x8 ov;
#pragma unroll
        for (int v = 0; v < 8; ++v) ov[v] = (half_t)acc[v];
        *(f16x8*)&corr[((size_t)lb * 256 + c0 + c) * HW + (size_t)(ph * 8 + u) * WW + pw * 8] = ov;
    }
}

// ---------------------------------------------------------------------------
// Fused LN(corr)*vd + 1x1 proj GEMM (K=256 split in 2, N=128) -> f32 out.
// Weights pre-converted f16 (wp16, row length 256).
// ---------------------------------------------------------------------------
__global__ __launch_bounds__(256)
void proj_kernel(const half_t* __restrict__ corr, const half_t* __restrict__ vd,
                 const float* __restrict__ lnw, const float* __restrict__ lnb,
                 const half_t* __restrict__ wp16, const float* __restrict__ wb,
                 float* __restrict__ out)
{
    __shared__ __attribute__((aligned(16))) half_t As[64][136];
    __shared__ __attribute__((aligned(16))) half_t Wsh[128][136];
    __shared__ float  redA[4][64];
    __shared__ float  redB[4][64];
    __shared__ float  mu_s[64], rs_s[64];

    const int tid = threadIdx.x;
    const int px  = tid & 63;
    const int g   = tid >> 6;
    const int l   = tid & 63;
    const int wv  = tid >> 6;

    const long p0  = (long)blockIdx.x * 64;
    const int  lb  = (int)(p0 / HW);
    const int  hw0 = (int)(p0 - (long)lb * HW);

    const half_t* cb = corr + (size_t)lb * 256 * HW + hw0 + px;
    const half_t* vb = vd   + (size_t)lb * 256 * HW + hw0 + px;

    float s1 = 0.f, s2 = 0.f;
#pragma unroll 8
    for (int j = 0; j < 64; ++j) {
        float cv = (float)cb[(size_t)(g * 64 + j) * HW];
        s1 += cv; s2 += cv * cv;
    }
    redA[g][px] = s1; redB[g][px] = s2;
    __syncthreads();
    if (tid < 64) {
        float su = redA[0][tid] + redA[1][tid] + redA[2][tid] + redA[3][tid];
        float sq = redB[0][tid] + redB[1][tid] + redB[2][tid] + redB[3][tid];
        float mu  = su * (1.f / 256.f);
        float var = sq * (1.f / 256.f) - mu * mu;
        mu_s[tid] = mu;
        rs_s[tid] = rsqrtf(var + 1e-5f);
    }
    __syncthreads();
    const float mu = mu_s[px], rs = rs_s[px];

    f32x4 acc[2][4];
#pragma unroll
    for (int nt = 0; nt < 2; ++nt)
#pragma unroll
        for (int pt = 0; pt < 4; ++pt) acc[nt][pt] = {0.f, 0.f, 0.f, 0.f};

    for (int kc = 0; kc < 2; ++kc) {
#pragma unroll 4
        for (int j = 0; j < 32; ++j) {
            int cl = g * 32 + j;
            int c  = kc * 128 + cl;
            float cv = (float)cb[(size_t)c * HW];
            float vv = (float)vb[(size_t)c * HW];
            As[px][cl] = (half_t)(((cv - mu) * rs * lnw[c] + lnb[c]) * vv);
        }
        // stage weights 128 x 128 f16: 2048 f16x8 loads, 8/thread
#pragma unroll
        for (int i = 0; i < 8; ++i) {
            int f  = i * 256 + tid;
            int n  = f >> 4;
            int x0 = (f & 15) * 8;
            *(f16x8*)&Wsh[n][x0] = *(const f16x8*)&wp16[(size_t)n * 256 + kc * 128 + x0];
        }
        __syncthreads();

#pragma unroll
        for (int nt = 0; nt < 2; ++nt) {
            f16x8 af[4];
#pragma unroll
            for (int kt = 0; kt < 4; ++kt)
                af[kt] = *(const f16x8*)&Wsh[wv * 32 + nt * 16 + (l & 15)][kt * 32 + (l >> 4) * 8];
#pragma unroll
            for (int pt = 0; pt < 4; ++pt) {
#pragma unroll
                for (int kt = 0; kt < 4; ++kt) {
                    f16x8 bfv = *(const f16x8*)&As[pt * 16 + (l & 15)][kt * 32 + (l >> 4) * 8];
                    acc[nt][pt] = __builtin_amdgcn_mfma_f32_16x16x32_f16(af[kt], bfv, acc[nt][pt], 0, 0, 0);
                }
            }
        }
        __syncthreads();
    }

#pragma unroll
    for (int nt = 0; nt < 2; ++nt)
#pragma unroll
        for (int pt = 0; pt < 4; ++pt)
#pragma unroll
            for (int r = 0; r < 4; ++r) {
                int n  = wv * 32 + nt * 16 + (l >> 4) * 4 + r;
                int po = pt * 16 + (l & 15);
                out[((size_t)lb * 128 + n) * HW + hw0 + po] = acc[nt][pt][r] + wb[n];
            }
}

// ---------------------------------------------------------------------------
extern "C" void kernel_launch(void* const* d_in, const int* in_sizes, int n_in,
                              void* d_out, int out_size, void* d_ws, size_t ws_size,
                              hipStream_t stream)
{
    const float* x        = (const float*)d_in[0];
    const float* evt      = (const float*)d_in[1];
    const float* ln_img_w = (const float*)d_in[2];
    const float* ln_img_b = (const float*)d_in[3];
    const float* ln_evt_w = (const float*)d_in[4];
    const float* ln_evt_b = (const float*)d_in[5];
    const float* q_w      = (const float*)d_in[6];
    const float* q_b      = (const float*)d_in[7];
    const float* q_dw_w   = (const float*)d_in[8];
    const float* q_dw_b   = (const float*)d_in[9];
    const float* kv_w     = (const float*)d_in[10];
    const float* kv_b     = (const float*)d_in[11];
    const float* kv_dw_w  = (const float*)d_in[12];
    const float* kv_dw_b  = (const float*)d_in[13];
    const float* ln_corr_w= (const float*)d_in[14];
    const float* ln_corr_b= (const float*)d_in[15];
    const float* proj_w   = (const float*)d_in[16];
    const float* proj_b   = (const float*)d_in[17];
    float* out = (float*)d_out;

    // f16 weight cache at the tail of ws (131072 halfs = 256 KB)
    const size_t wtail = (ws_size - 262144) & ~(size_t)255;
    half_t* wf  = (half_t*)((char*)d_ws + wtail);
    half_t* wq16 = wf;              // 256x128
    half_t* wkv16 = wf + 32768;     // 512x128
    half_t* wp16  = wf + 98304;     // 128x256

    const size_t per_b = (size_t)(256 + 512 + 256 + 256) * HW * sizeof(half_t); // 94.4 MB
    int PB = 1;
    if      (wtail >= 8 * per_b) PB = 8;
    else if (wtail >= 4 * per_b) PB = 4;
    else if (wtail >= 2 * per_b) PB = 2;

    half_t* q1   = (half_t*)d_ws;
    half_t* kv1  = q1  + (size_t)PB * 256 * HW;
    half_t* vd   = kv1 + (size_t)PB * 512 * HW;
    half_t* corr = vd  + (size_t)PB * 256 * HW;

    dim3 blk(256);
    wcvt_kernel<<<128, blk, 0, stream>>>(q_w, kv_w, proj_w, wf);

    for (int b0 = 0; b0 < BATCH; b0 += PB) {
        int nb = PB;
        ln_gemm_kernel<256><<<nb * PXB, blk, 0, stream>>>(
            x + (size_t)b0 * CIN * HW, ln_img_w, ln_img_b, wq16, q_b, q1);
        ln_gemm_kernel<512><<<nb * PXB, blk, 0, stream>>>(
            evt + (size_t)b0 * CIN * HW, ln_evt_w, ln_evt_b, wkv16, kv_b, kv1);
        corr_strip_kernel<<<nb * 24 * 128, blk, 0, stream>>>(
            q1, kv1, q_dw_w, q_dw_b, kv_dw_w, kv_dw_b, corr, vd);
        proj_kernel<<<nb * PXB, blk, 0, stream>>>(
            corr, vd, ln_corr_w, ln_corr_b, wp16, proj_b,
            out + (size_t)b0 * 128 * HW);
    }
}

// Round 7
// 797.088 us; speedup vs baseline: 1.3200x; 1.0295x over previous
//
#include <hip/hip_runtime.h>
#include <stdint.h>

#define BATCH 8
#define CIN   128
#define HH    192
#define WW    192
#define HW    (HH*WW)       // 36864
#define PXB   576           // (HW/64) pixel-tiles per batch
#define CH    2             // channels per corr block

typedef _Float16 half_t;
typedef _Float16 f16x8 __attribute__((ext_vector_type(8)));
typedef _Float16 f16x4 __attribute__((ext_vector_type(4)));
typedef _Float16 f16x2 __attribute__((ext_vector_type(2)));
typedef float    f32x4 __attribute__((ext_vector_type(4)));
typedef float    f32x16 __attribute__((ext_vector_type(16)));
typedef unsigned int u32;

// packed f16 dot2 with f32 accumulate (v_dot2_f32_f16)
__device__ __forceinline__ float DOT2(u32 a, u32 b, float c) {
#if __has_builtin(__builtin_amdgcn_fdot2)
    return __builtin_amdgcn_fdot2(__builtin_bit_cast(f16x2, a),
                                  __builtin_bit_cast(f16x2, b), c, false);
#else
    f16x2 av = __builtin_bit_cast(f16x2, a), bv = __builtin_bit_cast(f16x2, b);
    return c + (float)av[0] * (float)bv[0] + (float)av[1] * (float)bv[1];
#endif
}

// shared-memory layout for the MFMA kernels (51.5 KB -> 3 blocks/CU):
//   As  [64][136] f16   @ 0       (17408 B)
//   Wsh [128][136] f16  @ 17408   (34816 B)   } union: Cst[128][68] f32,
//   redA/redB           @ 17408   (2048 B)    }        red arrays (LN phase)
//   mu_s/rs_s           @ 52224   (512 B)
#define SMEM_BYTES 52736
#define WSH_OFF    17408
#define MU_OFF     52224

// ---------------------------------------------------------------------------
// One-shot weight f32 -> f16 conversion into workspace.
//   [0      .. 32768)  q_w   (256x128)
//   [32768  .. 98304)  kv_w  (512x128)
//   [98304  .. 131072) proj_w(128x256)
// ---------------------------------------------------------------------------
__global__ __launch_bounds__(256)
void wcvt_kernel(const float* __restrict__ qw, const float* __restrict__ kvw,
                 const float* __restrict__ pw, half_t* __restrict__ out)
{
    int q = blockIdx.x * 256 + threadIdx.x;      // float4 index, 32768 total
    if (q >= 32768) return;
    int idx = q * 4;
    const float* src;
    int off;
    if (idx < 32768)      { src = qw;  off = idx; }
    else if (idx < 98304) { src = kvw; off = idx - 32768; }
    else                  { src = pw;  off = idx - 98304; }
    float4 v = *(const float4*)&src[off];
    f16x4 o = { (half_t)v.x, (half_t)v.y, (half_t)v.z, (half_t)v.w };
    *(f16x4*)&out[idx] = o;
}

// ---------------------------------------------------------------------------
// Fused LayerNorm(channel) + 1x1 conv GEMM via MFMA 32x32x16 f16.
// Block: 256 thr, 64 px; nc loop over OC/128. Wave w owns oc rows w*32..+31,
// both 32-px halves. Epilogue: acc -> f32 LDS transpose (Wsh union) ->
// coalesced b128 stores.
// ---------------------------------------------------------------------------
template<int OC>
__global__ __launch_bounds__(256)
void ln_gemm_kernel(const float* __restrict__ x,
                    const float* __restrict__ lnw, const float* __restrict__ lnb,
                    const half_t* __restrict__ wf16, const float* __restrict__ wb,
                    half_t* __restrict__ out)
{
    __shared__ __attribute__((aligned(16))) char smem[SMEM_BYTES];
    half_t (*As)[136]  = (half_t(*)[136])smem;
    half_t (*Wsh)[136] = (half_t(*)[136])(smem + WSH_OFF);
    float  (*Cst)[68]  = (float (*)[68]) (smem + WSH_OFF);
    float* redA = (float*)(smem + WSH_OFF);
    float* redB = (float*)(smem + WSH_OFF + 1024);
    float* mu_s = (float*)(smem + MU_OFF);
    float* rs_s = mu_s + 64;

    const int tid  = threadIdx.x;
    const int px   = tid & 63;
    const int g    = tid >> 6;
    const int l    = tid & 63;
    const int w    = tid >> 6;
    const int lrow = l & 31;
    const int lk   = (l >> 5) * 8;

    const long p0  = (long)blockIdx.x * 64;
    const int  b   = (int)(p0 / HW);
    const int  hw0 = (int)(p0 - (long)b * HW);

    // ---- LN stats ----
    const float* xb = x + (size_t)b * CIN * HW + hw0 + px;
    float vals[32];
    float s1 = 0.f, s2 = 0.f;
#pragma unroll
    for (int j = 0; j < 32; ++j) {
        float v = xb[(size_t)(g * 32 + j) * HW];
        vals[j] = v; s1 += v; s2 += v * v;
    }
    redA[g * 64 + px] = s1; redB[g * 64 + px] = s2;
    __syncthreads();
    if (tid < 64) {
        float su = redA[tid] + redA[64 + tid] + redA[128 + tid] + redA[192 + tid];
        float sq = redB[tid] + redB[64 + tid] + redB[128 + tid] + redB[192 + tid];
        float mu  = su * (1.f / 128.f);
        float var = sq * (1.f / 128.f) - mu * mu;
        mu_s[tid] = mu;
        rs_s[tid] = rsqrtf(var + 1e-5f);
    }
    __syncthreads();
    {
        float mu = mu_s[px], rs = rs_s[px];
#pragma unroll
        for (int m = 0; m < 4; ++m) {
            f16x8 o;
#pragma unroll
            for (int j = 0; j < 8; ++j) {
                int c = g * 32 + m * 8 + j;
                o[j] = (half_t)((vals[m * 8 + j] - mu) * rs * lnw[c] + lnb[c]);
            }
            *(f16x8*)&As[px][g * 32 + m * 8] = o;
        }
    }

    // ---- nc loop: 128 output channels per iteration ----
    for (int nc = 0; nc < OC / 128; ++nc) {
        const int n0 = nc * 128;
        if (nc) __syncthreads();          // prev epilogue readers done
#pragma unroll
        for (int i = 0; i < 8; ++i) {
            int f  = i * 256 + tid;       // 2048 b128 loads
            int n  = f >> 4;
            int xh = (f & 15) * 8;
            *(f16x8*)&Wsh[n][xh] = *(const f16x8*)&wf16[(size_t)(n0 + n) * CIN + xh];
        }
        __syncthreads();

        f16x8 af[8];
#pragma unroll
        for (int kk = 0; kk < 8; ++kk)
            af[kk] = *(const f16x8*)&Wsh[w * 32 + lrow][kk * 16 + lk];

        f32x16 acc0, acc1;
#pragma unroll
        for (int i = 0; i < 16; ++i) { acc0[i] = 0.f; acc1[i] = 0.f; }
#pragma unroll
        for (int kk = 0; kk < 8; ++kk) {
            f16x8 b0 = *(const f16x8*)&As[lrow][kk * 16 + lk];
            f16x8 b1 = *(const f16x8*)&As[32 + lrow][kk * 16 + lk];
            acc0 = __builtin_amdgcn_mfma_f32_32x32x16_f16(af[kk], b0, acc0, 0, 0, 0);
            acc1 = __builtin_amdgcn_mfma_f32_32x32x16_f16(af[kk], b1, acc1, 0, 0, 0);
        }
        __syncthreads();                  // all waves done with Wsh/As reads

        // transpose: D[row=oc][col=px], row=(r&3)+8*(r>>2)+4*(l>>5), col=lrow
#pragma unroll
        for (int r = 0; r < 16; ++r) {
            int oc = w * 32 + (r & 3) + 8 * (r >> 2) + 4 * (l >> 5);
            Cst[oc][lrow]      = acc0[r];
            Cst[oc][32 + lrow] = acc1[r];
        }
        __syncthreads();

#pragma unroll
        for (int i = 0; i < 4; ++i) {
            int idx = i * 256 + tid;      // 1024 b128 stores
            int oc  = idx >> 3;
            int pxg = idx & 7;
            const float4 a = *(const float4*)&Cst[oc][pxg * 8];
            const float4 c = *(const float4*)&Cst[oc][pxg * 8 + 4];
            float bias = wb[n0 + oc];
            f16x8 o = { (half_t)(a.x + bias), (half_t)(a.y + bias),
                        (half_t)(a.z + bias), (half_t)(a.w + bias),
                        (half_t)(c.x + bias), (half_t)(c.y + bias),
                        (half_t)(c.z + bias), (half_t)(c.w + bias) };
            *(f16x8*)&out[((size_t)b * OC + n0 + oc) * HW + hw0 + pxg * 8] = o;
        }
    }
}

// ---------------------------------------------------------------------------
// Strip-based fused dwconv(q,k,v) + per-patch 8x8 circular conv (round-6 v3,
// unchanged: 256 thr, dot2 stage C, krev single + alignbit windows).
// ---------------------------------------------------------------------------
__global__ __launch_bounds__(256)
void corr_strip_kernel(const half_t* __restrict__ q1, const half_t* __restrict__ kv1,
                       const float* __restrict__ qw, const float* __restrict__ qb,
                       const float* __restrict__ kw, const float* __restrict__ kb,
                       half_t* __restrict__ corr, half_t* __restrict__ vd)
{
    __shared__ __attribute__((aligned(16))) half_t raw[6][10][208];
    __shared__ __attribute__((aligned(16))) half_t qd[2][8][192];
    __shared__ __attribute__((aligned(16))) half_t krev[2][8][200];

    const int bid = blockIdx.x;
    const int cg  = bid & 127;
    const int ph  = (bid >> 7) % 24;
    const int lb  = (bid >> 7) / 24;
    const int c0  = cg * CH;
    const int tid = threadIdx.x;

    if (tid < 120) {
        int side = tid & 1;
        int row  = (tid >> 1) % 10;
        int a    = tid / 20;
        f16x8 z = {};
        *(f16x8*)&raw[a][row][side ? 200 : 0] = z;
    }

    for (int i = 0; i < 6; ++i) {
        int idx = tid + 256 * i;
        if (idx >= 1440) break;
        int vec = idx % 24;
        int row = (idx / 24) % 10;
        int a   = idx / 240;
        int ch  = a & 1;
        int gh  = ph * 8 - 1 + row;
        f16x8 v = {};
        if (gh >= 0 && gh < HH) {
            const half_t* src;
            if (a < 2)      src = q1  + ((size_t)lb * 256 + c0 + ch) * HW;
            else if (a < 4) src = kv1 + ((size_t)lb * 512 + c0 + ch) * HW;
            else            src = kv1 + ((size_t)lb * 512 + 256 + c0 + ch) * HW;
            v = *(const f16x8*)&src[(size_t)gh * WW + vec * 8];
        }
        *(f16x8*)&raw[a][row][8 + vec * 8] = v;
    }
    __syncthreads();

    for (int i = 0; i < 5; ++i) {
        int unit = tid + 256 * i;
        if (unit >= 1152) break;
        int xg = unit % 24;
        int u  = (unit / 24) % 8;
        int a  = unit / 192;
        int ch = a & 1;
        const half_t (*rw)[208] = raw[a];
        const float* wt;
        float bias;
        if (a < 2)      { wt = qw + (size_t)(c0 + ch) * 9;       bias = qb[c0 + ch]; }
        else if (a < 4) { wt = kw + (size_t)(c0 + ch) * 9;       bias = kb[c0 + ch]; }
        else            { wt = kw + (size_t)(256 + c0 + ch) * 9; bias = kb[256 + c0 + ch]; }
        int x0 = xg * 8;
        float r0[10], r1[10], r2[10];
#pragma unroll
        for (int j = 0; j < 10; ++j) {
            r0[j] = (float)rw[u + 0][7 + x0 + j];
            r1[j] = (float)rw[u + 1][7 + x0 + j];
            r2[j] = (float)rw[u + 2][7 + x0 + j];
        }
        float acc[8];
#pragma unroll
        for (int xx = 0; xx < 8; ++xx) acc[xx] = bias;
#pragma unroll
        for (int dx = 0; dx < 3; ++dx) {
            float w0 = wt[dx], w1 = wt[3 + dx], w2 = wt[6 + dx];
#pragma unroll
            for (int xx = 0; xx < 8; ++xx) {
                acc[xx] += r0[xx + dx] * w0 + r1[xx + dx] * w1 + r2[xx + dx] * w2;
            }
        }
        if (a < 2) {
            f16x8 o;
#pragma unroll
            for (int xx = 0; xx < 8; ++xx) o[xx] = (half_t)acc[xx];
            *(f16x8*)&qd[ch][u][x0] = o;
        } else if (a < 4) {
            f16x8 o;
            o[0] = (half_t)acc[0];
#pragma unroll
            for (int j = 1; j < 8; ++j) o[j] = (half_t)acc[8 - j];
            *(f16x8*)&krev[ch][u][xg * 8] = o;
        } else {
            f16x8 o;
#pragma unroll
            for (int xx = 0; xx < 8; ++xx) o[xx] = (half_t)acc[xx];
            *(f16x8*)&vd[((size_t)lb * 256 + c0 + ch) * HW + (size_t)(ph * 8 + u) * WW + x0] = o;
        }
    }
    __syncthreads();

    for (int i = 0; i < 2; ++i) {
        int unit = tid + 256 * i;
        if (unit >= 384) break;
        int c   = unit / 192;
        int rem = unit % 192;
        int pw  = rem >> 3;
        int u   = rem & 7;
        float acc[8];
#pragma unroll
        for (int v = 0; v < 8; ++v) acc[v] = 0.f;
#pragma unroll
        for (int s = 0; s < 8; ++s) {
            int r = (u - s) & 7;
            uint4 q4 = *(const uint4*)&qd[c][s][pw * 8];
            uint4 k4 = *(const uint4*)&krev[c][r][pw * 8];
            u32 Q[4] = {q4.x, q4.y, q4.z, q4.w};
            u32 K[4] = {k4.x, k4.y, k4.z, k4.w};
            u32 S[4];
#pragma unroll
            for (int m = 0; m < 4; ++m) S[m] = (K[m] >> 16) | (K[(m + 1) & 3] << 16);
#pragma unroll
            for (int v = 0; v < 8; ++v) {
                const int o = 8 - v;
#pragma unroll
                for (int tt = 0; tt < 4; ++tt) {
                    u32 pr = (o & 1) ? S[(((o - 1) >> 1) + tt) & 3]
                                     : K[((o >> 1) + tt) & 3];
                    acc[v] = DOT2(Q[tt], pr, acc[v]);
                }
            }
        }
        f16x8 ov;
#pragma unroll
        for (int v = 0; v < 8; ++v) ov[v] = (half_t)acc[v];
        *(f16x8*)&corr[((size_t)lb * 256 + c0 + c) * HW + (size_t)(ph * 8 + u) * WW + pw * 8] = ov;
    }
}

// ---------------------------------------------------------------------------
// Fused LN(corr)*vd + 1x1 proj GEMM via MFMA 32x32x16 (K=256 in 2 halves,
// N=128) -> f32 out, vectorized float4 epilogue.
// ---------------------------------------------------------------------------
__global__ __launch_bounds__(256)
void proj_kernel(const half_t* __restrict__ corr, const half_t* __restrict__ vd,
                 const float* __restrict__ lnw, const float* __restrict__ lnb,
                 const half_t* __restrict__ wp16, const float* __restrict__ wb,
                 float* __restrict__ out)
{
    __shared__ __attribute__((aligned(16))) char smem[SMEM_BYTES];
    half_t (*As)[136]  = (half_t(*)[136])smem;
    half_t (*Wsh)[136] = (half_t(*)[136])(smem + WSH_OFF);
    float  (*Cst)[68]  = (float (*)[68]) (smem + WSH_OFF);
    float* redA = (float*)(smem + WSH_OFF);
    float* redB = (float*)(smem + WSH_OFF + 1024);
    float* mu_s = (float*)(smem + MU_OFF);
    float* rs_s = mu_s + 64;

    const int tid  = threadIdx.x;
    const int px   = tid & 63;
    const int g    = tid >> 6;
    const int l    = tid & 63;
    const int w    = tid >> 6;
    const int lrow = l & 31;
    const int lk   = (l >> 5) * 8;

    const long p0  = (long)blockIdx.x * 64;
    const int  lb  = (int)(p0 / HW);
    const int  hw0 = (int)(p0 - (long)lb * HW);

    const half_t* cb = corr + (size_t)lb * 256 * HW + hw0 + px;
    const half_t* vb = vd   + (size_t)lb * 256 * HW + hw0 + px;

    float s1 = 0.f, s2 = 0.f;
#pragma unroll 8
    for (int j = 0; j < 64; ++j) {
        float cv = (float)cb[(size_t)(g * 64 + j) * HW];
        s1 += cv; s2 += cv * cv;
    }
    redA[g * 64 + px] = s1; redB[g * 64 + px] = s2;
    __syncthreads();
    if (tid < 64) {
        float su = redA[tid] + redA[64 + tid] + redA[128 + tid] + redA[192 + tid];
        float sq = redB[tid] + redB[64 + tid] + redB[128 + tid] + redB[192 + tid];
        float mu  = su * (1.f / 256.f);
        float var = sq * (1.f / 256.f) - mu * mu;
        mu_s[tid] = mu;
        rs_s[tid] = rsqrtf(var + 1e-5f);
    }
    __syncthreads();
    const float mu = mu_s[px], rs = rs_s[px];

    f32x16 acc0, acc1;
#pragma unroll
    for (int i = 0; i < 16; ++i) { acc0[i] = 0.f; acc1[i] = 0.f; }

    for (int kc = 0; kc < 2; ++kc) {
        if (kc) __syncthreads();          // kc=0 MFMA readers done with As/Wsh
#pragma unroll
        for (int m = 0; m < 4; ++m) {
            f16x8 o;
#pragma unroll
            for (int j = 0; j < 8; ++j) {
                int c = kc * 128 + g * 32 + m * 8 + j;
                float cv = (float)cb[(size_t)c * HW];
                float vv = (float)vb[(size_t)c * HW];
                o[j] = (half_t)(((cv - mu) * rs * lnw[c] + lnb[c]) * vv);
            }
            *(f16x8*)&As[px][g * 32 + m * 8] = o;
        }
#pragma unroll
        for (int i = 0; i < 8; ++i) {
            int f  = i * 256 + tid;
            int n  = f >> 4;
            int xh = (f & 15) * 8;
            *(f16x8*)&Wsh[n][xh] = *(const f16x8*)&wp16[(size_t)n * 256 + kc * 128 + xh];
        }
        __syncthreads();

        f16x8 af[8];
#pragma unroll
        for (int kk = 0; kk < 8; ++kk)
            af[kk] = *(const f16x8*)&Wsh[w * 32 + lrow][kk * 16 + lk];
#pragma unroll
        for (int kk = 0; kk < 8; ++kk) {
            f16x8 b0 = *(const f16x8*)&As[lrow][kk * 16 + lk];
            f16x8 b1 = *(const f16x8*)&As[32 + lrow][kk * 16 + lk];
            acc0 = __builtin_amdgcn_mfma_f32_32x32x16_f16(af[kk], b0, acc0, 0, 0, 0);
            acc1 = __builtin_amdgcn_mfma_f32_32x32x16_f16(af[kk], b1, acc1, 0, 0, 0);
        }
    }
    __syncthreads();

#pragma unroll
    for (int r = 0; r < 16; ++r) {
        int oc = w * 32 + (r & 3) + 8 * (r >> 2) + 4 * (l >> 5);
        Cst[oc][lrow]      = acc0[r];
        Cst[oc][32 + lrow] = acc1[r];
    }
    __syncthreads();

#pragma unroll
    for (int i = 0; i < 8; ++i) {
        int idx = i * 256 + tid;          // 2048 float4 stores
        int oc  = idx >> 4;
        int pxq = idx & 15;
        float4 a = *(const float4*)&Cst[oc][pxq * 4];
        float bias = wb[oc];
        a.x += bias; a.y += bias; a.z += bias; a.w += bias;
        *(float4*)&out[((size_t)lb * 128 + oc) * HW + hw0 + pxq * 4] = a;
    }
}

// ---------------------------------------------------------------------------
extern "C" void kernel_launch(void* const* d_in, const int* in_sizes, int n_in,
                              void* d_out, int out_size, void* d_ws, size_t ws_size,
                              hipStream_t stream)
{
    const float* x        = (const float*)d_in[0];
    const float* evt      = (const float*)d_in[1];
    const float* ln_img_w = (const float*)d_in[2];
    const float* ln_img_b = (const float*)d_in[3];
    const float* ln_evt_w = (const float*)d_in[4];
    const float* ln_evt_b = (const float*)d_in[5];
    const float* q_w      = (const float*)d_in[6];
    const float* q_b      = (const float*)d_in[7];
    const float* q_dw_w   = (const float*)d_in[8];
    const float* q_dw_b   = (const float*)d_in[9];
    const float* kv_w     = (const float*)d_in[10];
    const float* kv_b     = (const float*)d_in[11];
    const float* kv_dw_w  = (const float*)d_in[12];
    const float* kv_dw_b  = (const float*)d_in[13];
    const float* ln_corr_w= (const float*)d_in[14];
    const float* ln_corr_b= (const float*)d_in[15];
    const float* proj_w   = (const float*)d_in[16];
    const float* proj_b   = (const float*)d_in[17];
    float* out = (float*)d_out;

    // f16 weight cache at the tail of ws (131072 halfs = 256 KB)
    const size_t wtail = (ws_size - 262144) & ~(size_t)255;
    half_t* wf    = (half_t*)((char*)d_ws + wtail);
    half_t* wq16  = wf;             // 256x128
    half_t* wkv16 = wf + 32768;     // 512x128
    half_t* wp16  = wf + 98304;     // 128x256

    const size_t per_b = (size_t)(256 + 512 + 256 + 256) * HW * sizeof(half_t); // 94.4 MB
    int PB = 1;
    if      (wtail >= 8 * per_b) PB = 8;
    else if (wtail >= 4 * per_b) PB = 4;
    else if (wtail >= 2 * per_b) PB = 2;

    half_t* q1   = (half_t*)d_ws;
    half_t* kv1  = q1  + (size_t)PB * 256 * HW;
    half_t* vd   = kv1 + (size_t)PB * 512 * HW;
    half_t* corr = vd  + (size_t)PB * 256 * HW;

    dim3 blk(256);
    wcvt_kernel<<<128, blk, 0, stream>>>(q_w, kv_w, proj_w, wf);

    for (int b0 = 0; b0 < BATCH; b0 += PB) {
        int nb = PB;
        ln_gemm_kernel<256><<<nb * PXB, blk, 0, stream>>>(
            x + (size_t)b0 * CIN * HW, ln_img_w, ln_img_b, wq16, q_b, q1);
        ln_gemm_kernel<512><<<nb * PXB, blk, 0, stream>>>(
            evt + (size_t)b0 * CIN * HW, ln_evt_w, ln_evt_b, wkv16, kv_b, kv1);
        corr_strip_kernel<<<nb * 24 * 128, blk, 0, stream>>>(
            q1, kv1, q_dw_w, q_dw_b, kv_dw_w, kv_dw_b, corr, vd);
        proj_kernel<<<nb * PXB, blk, 0, stream>>>(
            corr, vd, ln_corr_w, ln_corr_b, wp16, proj_b,
            out + (size_t)b0 * 128 * HW);
    }
}

// Round 8
// 733.100 us; speedup vs baseline: 1.4352x; 1.0873x over previous
//
#include <hip/hip_runtime.h>
#include <stdint.h>

#define BATCH 8
#define CIN   128
#define HH    192
#define WW    192
#define HW    (HH*WW)       // 36864
#define PXB   576           // (HW/64) pixel-tiles per batch
#define CH    2             // channels per corr block

typedef _Float16 half_t;
typedef _Float16 f16x8 __attribute__((ext_vector_type(8)));
typedef _Float16 f16x4 __attribute__((ext_vector_type(4)));
typedef _Float16 f16x2 __attribute__((ext_vector_type(2)));
typedef float    f32x4 __attribute__((ext_vector_type(4)));
typedef float    f32x16 __attribute__((ext_vector_type(16)));
typedef unsigned int u32;

// packed f16 dot2 with f32 accumulate (v_dot2_f32_f16)
__device__ __forceinline__ float DOT2(u32 a, u32 b, float c) {
#if __has_builtin(__builtin_amdgcn_fdot2)
    return __builtin_amdgcn_fdot2(__builtin_bit_cast(f16x2, a),
                                  __builtin_bit_cast(f16x2, b), c, false);
#else
    f16x2 av = __builtin_bit_cast(f16x2, a), bv = __builtin_bit_cast(f16x2, b);
    return c + (float)av[0] * (float)bv[0] + (float)av[1] * (float)bv[1];
#endif
}

// shared-memory layout for the MFMA kernels (51.5 KB -> 3 blocks/CU):
#define SMEM_BYTES 52736
#define WSH_OFF    17408
#define MU_OFF     52224

// ---------------------------------------------------------------------------
// One-shot weight f32 -> f16 conversion into workspace.
//   [0      .. 32768)   q_w    (256x128)
//   [32768  .. 98304)   kv_w   (512x128)
//   [98304  .. 131072)  proj_w (128x256)
//   [131072 .. 133376)  q_dw_w (256x9)
//   [133376 .. 137984)  kv_dw_w(512x9)
// ---------------------------------------------------------------------------
__global__ __launch_bounds__(256)
void wcvt_kernel(const float* __restrict__ qw, const float* __restrict__ kvw,
                 const float* __restrict__ pw, const float* __restrict__ qdw,
                 const float* __restrict__ kvdw, half_t* __restrict__ out)
{
    int q = blockIdx.x * 256 + threadIdx.x;      // float4 index, 34496 total
    if (q >= 34496) return;
    int idx = q * 4;
    const float* src;
    int off;
    if (idx < 32768)       { src = qw;   off = idx; }
    else if (idx < 98304)  { src = kvw;  off = idx - 32768; }
    else if (idx < 131072) { src = pw;   off = idx - 98304; }
    else if (idx < 133376) { src = qdw;  off = idx - 131072; }
    else                   { src = kvdw; off = idx - 133376; }
    float4 v = *(const float4*)&src[off];
    f16x4 o = { (half_t)v.x, (half_t)v.y, (half_t)v.z, (half_t)v.w };
    *(f16x4*)&out[idx] = o;
}

// ---------------------------------------------------------------------------
// Fused LayerNorm(channel) + 1x1 conv GEMM via MFMA 32x32x16 f16. (unchanged)
// ---------------------------------------------------------------------------
template<int OC>
__global__ __launch_bounds__(256)
void ln_gemm_kernel(const float* __restrict__ x,
                    const float* __restrict__ lnw, const float* __restrict__ lnb,
                    const half_t* __restrict__ wf16, const float* __restrict__ wb,
                    half_t* __restrict__ out)
{
    __shared__ __attribute__((aligned(16))) char smem[SMEM_BYTES];
    half_t (*As)[136]  = (half_t(*)[136])smem;
    half_t (*Wsh)[136] = (half_t(*)[136])(smem + WSH_OFF);
    float  (*Cst)[68]  = (float (*)[68]) (smem + WSH_OFF);
    float* redA = (float*)(smem + WSH_OFF);
    float* redB = (float*)(smem + WSH_OFF + 1024);
    float* mu_s = (float*)(smem + MU_OFF);
    float* rs_s = mu_s + 64;

    const int tid  = threadIdx.x;
    const int px   = tid & 63;
    const int g    = tid >> 6;
    const int l    = tid & 63;
    const int w    = tid >> 6;
    const int lrow = l & 31;
    const int lk   = (l >> 5) * 8;

    const long p0  = (long)blockIdx.x * 64;
    const int  b   = (int)(p0 / HW);
    const int  hw0 = (int)(p0 - (long)b * HW);

    const float* xb = x + (size_t)b * CIN * HW + hw0 + px;
    float vals[32];
    float s1 = 0.f, s2 = 0.f;
#pragma unroll
    for (int j = 0; j < 32; ++j) {
        float v = xb[(size_t)(g * 32 + j) * HW];
        vals[j] = v; s1 += v; s2 += v * v;
    }
    redA[g * 64 + px] = s1; redB[g * 64 + px] = s2;
    __syncthreads();
    if (tid < 64) {
        float su = redA[tid] + redA[64 + tid] + redA[128 + tid] + redA[192 + tid];
        float sq = redB[tid] + redB[64 + tid] + redB[128 + tid] + redB[192 + tid];
        float mu  = su * (1.f / 128.f);
        float var = sq * (1.f / 128.f) - mu * mu;
        mu_s[tid] = mu;
        rs_s[tid] = rsqrtf(var + 1e-5f);
    }
    __syncthreads();
    {
        float mu = mu_s[px], rs = rs_s[px];
#pragma unroll
        for (int m = 0; m < 4; ++m) {
            f16x8 o;
#pragma unroll
            for (int j = 0; j < 8; ++j) {
                int c = g * 32 + m * 8 + j;
                o[j] = (half_t)((vals[m * 8 + j] - mu) * rs * lnw[c] + lnb[c]);
            }
            *(f16x8*)&As[px][g * 32 + m * 8] = o;
        }
    }

    for (int nc = 0; nc < OC / 128; ++nc) {
        const int n0 = nc * 128;
        if (nc) __syncthreads();
#pragma unroll
        for (int i = 0; i < 8; ++i) {
            int f  = i * 256 + tid;
            int n  = f >> 4;
            int xh = (f & 15) * 8;
            *(f16x8*)&Wsh[n][xh] = *(const f16x8*)&wf16[(size_t)(n0 + n) * CIN + xh];
        }
        __syncthreads();

        f16x8 af[8];
#pragma unroll
        for (int kk = 0; kk < 8; ++kk)
            af[kk] = *(const f16x8*)&Wsh[w * 32 + lrow][kk * 16 + lk];

        f32x16 acc0, acc1;
#pragma unroll
        for (int i = 0; i < 16; ++i) { acc0[i] = 0.f; acc1[i] = 0.f; }
#pragma unroll
        for (int kk = 0; kk < 8; ++kk) {
            f16x8 b0 = *(const f16x8*)&As[lrow][kk * 16 + lk];
            f16x8 b1 = *(const f16x8*)&As[32 + lrow][kk * 16 + lk];
            acc0 = __builtin_amdgcn_mfma_f32_32x32x16_f16(af[kk], b0, acc0, 0, 0, 0);
            acc1 = __builtin_amdgcn_mfma_f32_32x32x16_f16(af[kk], b1, acc1, 0, 0, 0);
        }
        __syncthreads();

#pragma unroll
        for (int r = 0; r < 16; ++r) {
            int oc = w * 32 + (r & 3) + 8 * (r >> 2) + 4 * (l >> 5);
            Cst[oc][lrow]      = acc0[r];
            Cst[oc][32 + lrow] = acc1[r];
        }
        __syncthreads();

#pragma unroll
        for (int i = 0; i < 4; ++i) {
            int idx = i * 256 + tid;
            int oc  = idx >> 3;
            int pxg = idx & 7;
            const float4 a = *(const float4*)&Cst[oc][pxg * 8];
            const float4 c = *(const float4*)&Cst[oc][pxg * 8 + 4];
            float bias = wb[n0 + oc];
            f16x8 o = { (half_t)(a.x + bias), (half_t)(a.y + bias),
                        (half_t)(a.z + bias), (half_t)(a.w + bias),
                        (half_t)(c.x + bias), (half_t)(c.y + bias),
                        (half_t)(c.z + bias), (half_t)(c.w + bias) };
            *(f16x8*)&out[((size_t)b * OC + n0 + oc) * HW + hw0 + pxg * 8] = o;
        }
    }
}

// ---------------------------------------------------------------------------
// Strip-based fused dwconv(q,k,v) + per-patch 8x8 circular conv, v4.
// Stage B vectorized: 576 units of 16 outputs; per row 4x b128 LDS loads +
// alignbit pair-extraction + v_dot2_f32_f16 3-tap conv (f16 weights).
// Stages A and C unchanged from round 6.
// ---------------------------------------------------------------------------
__global__ __launch_bounds__(256)
void corr_strip_kernel(const half_t* __restrict__ q1, const half_t* __restrict__ kv1,
                       const half_t* __restrict__ qdw16, const float* __restrict__ qb,
                       const half_t* __restrict__ kdw16, const float* __restrict__ kb,
                       half_t* __restrict__ corr, half_t* __restrict__ vd)
{
    __shared__ __attribute__((aligned(16))) half_t raw[6][10][208];
    __shared__ __attribute__((aligned(16))) half_t qd[2][8][192];
    __shared__ __attribute__((aligned(16))) half_t krev[2][8][200];

    const int bid = blockIdx.x;
    const int cg  = bid & 127;
    const int ph  = (bid >> 7) % 24;
    const int lb  = (bid >> 7) / 24;
    const int c0  = cg * CH;
    const int tid = threadIdx.x;

    // ---- zero the column-halo slots ----
    if (tid < 120) {
        int side = tid & 1;
        int row  = (tid >> 1) % 10;
        int a    = tid / 20;
        f16x8 z = {};
        *(f16x8*)&raw[a][row][side ? 200 : 0] = z;
    }

    // ---- stage A: coalesced strip loads ----
    for (int i = 0; i < 6; ++i) {
        int idx = tid + 256 * i;
        if (idx >= 1440) break;
        int vec = idx % 24;
        int row = (idx / 24) % 10;
        int a   = idx / 240;
        int ch  = a & 1;
        int gh  = ph * 8 - 1 + row;
        f16x8 v = {};
        if (gh >= 0 && gh < HH) {
            const half_t* src;
            if (a < 2)      src = q1  + ((size_t)lb * 256 + c0 + ch) * HW;
            else if (a < 4) src = kv1 + ((size_t)lb * 512 + c0 + ch) * HW;
            else            src = kv1 + ((size_t)lb * 512 + 256 + c0 + ch) * HW;
            v = *(const f16x8*)&src[(size_t)gh * WW + vec * 8];
        }
        *(f16x8*)&raw[a][row][8 + vec * 8] = v;
    }
    __syncthreads();

    // ---- stage B: dwconv via dot2; 576 units = (a, u, xg2), 16 outputs ----
    for (int i = 0; i < 3; ++i) {
        int unit = tid + 256 * i;
        if (unit >= 576) break;
        int xg2 = unit % 12;
        int u   = (unit / 12) % 8;
        int a   = unit / 96;            // 0..5
        int ch  = a & 1;
        const half_t (*rw)[208] = raw[a];
        const half_t* wt;
        float bias;
        if (a < 2)      { wt = qdw16 + (size_t)(c0 + ch) * 9;       bias = qb[c0 + ch]; }
        else if (a < 4) { wt = kdw16 + (size_t)(c0 + ch) * 9;       bias = kb[c0 + ch]; }
        else            { wt = kdw16 + (size_t)(256 + c0 + ch) * 9; bias = kb[256 + c0 + ch]; }
        u32 w01[3], w2z[3];
#pragma unroll
        for (int dy = 0; dy < 3; ++dy) {
            u32 a0 = (u32)__builtin_bit_cast(unsigned short, wt[dy * 3 + 0]);
            u32 a1 = (u32)__builtin_bit_cast(unsigned short, wt[dy * 3 + 1]);
            u32 a2 = (u32)__builtin_bit_cast(unsigned short, wt[dy * 3 + 2]);
            w01[dy] = a0 | (a1 << 16);
            w2z[dy] = a2;
        }
        const int x0 = xg2 * 16;        // raw-col base of aligned window
        float acc[16];
#pragma unroll
        for (int xx = 0; xx < 16; ++xx) acc[xx] = bias;
#pragma unroll
        for (int dy = 0; dy < 3; ++dy) {
            const half_t* rowp = &rw[u + dy][x0];
            uint4 c0v = *(const uint4*)(rowp);        // halfs x0+0 .. +7
            uint4 c1v = *(const uint4*)(rowp + 8);
            uint4 c2v = *(const uint4*)(rowp + 16);
            uint4 c3v = *(const uint4*)(rowp + 24);
            u32 H0 = c0v.x, H1 = c0v.y, H2 = c0v.z, H3 = c0v.w;
            u32 H4 = c1v.x, H5 = c1v.y, H6 = c1v.z, H7 = c1v.w;
            u32 H8 = c2v.x, H9 = c2v.y, H10 = c2v.z, H11 = c2v.w;
            u32 H12 = c3v.x;
            u32 H[13] = {H0,H1,H2,H3,H4,H5,H6,H7,H8,H9,H10,H11,H12};
            u32 A[12];
#pragma unroll
            for (int m = 3; m < 12; ++m) A[m] = (H[m] >> 16) | (H[m + 1] << 16);
            // out[xx] (global col x0-8+xx? no: outputs global x = x0-8+...) —
            // outputs are global cols (x0-8)+xx? raw col = global+8, and
            // out global col X uses raw cols X+7..X+9. With unit outputs
            // global X0..X0+15 where X0 = xg2*16 - 8 + 8 = xg2*16? Outputs
            // global cols xg2*16 + xx need raw (xg2*16+xx)+7.. — our H window
            // starts at raw x0 = xg2*16, so pair indices below are raw-relative.
#pragma unroll
            for (int xx = 0; xx < 16; ++xx) {
                u32 p01 = (xx & 1) ? H[(7 + xx) >> 1] : A[3 + (xx >> 1)];
                u32 p2  = (xx & 1) ? H[(9 + xx) >> 1] : A[4 + (xx >> 1)];
                acc[xx] = DOT2(p01, w01[dy], acc[xx]);
                acc[xx] = DOT2(p2,  w2z[dy], acc[xx]);
            }
        }
        // outputs cover global cols gx0 .. gx0+15, gx0 = x0 - 8 + 8 = x0 - ... :
        // raw col (7+xx)+x0 = global (x0+xx-1)  => global X = x0 + xx - 1 + ...
        // Check: out xx uses raw x0+7+xx = global x0+xx-1 (left tap) => center
        // global x0+xx. So outputs are global cols x0+0 .. x0+15 with x0=16*xg2. OK.
        f16x8 o0, o1;
#pragma unroll
        for (int xx = 0; xx < 8; ++xx) { o0[xx] = (half_t)acc[xx]; o1[xx] = (half_t)acc[8 + xx]; }
        if (a < 2) {
            *(f16x8*)&qd[ch][u][x0]     = o0;
            *(f16x8*)&qd[ch][u][x0 + 8] = o1;
        } else if (a < 4) {
            f16x8 r0v, r1v;
            r0v[0] = (half_t)acc[0];
            r1v[0] = (half_t)acc[8];
#pragma unroll
            for (int j = 1; j < 8; ++j) {
                r0v[j] = (half_t)acc[8 - j];
                r1v[j] = (half_t)acc[16 - j];
            }
            *(f16x8*)&krev[ch][u][x0]     = r0v;
            *(f16x8*)&krev[ch][u][x0 + 8] = r1v;
        } else {
            half_t* dst = &vd[((size_t)lb * 256 + c0 + ch) * HW + (size_t)(ph * 8 + u) * WW + x0];
            *(f16x8*)dst       = o0;
            *(f16x8*)(dst + 8) = o1;
        }
    }
    __syncthreads();

    // ---- stage C: circular conv via dot2 + register-circular windows ----
    for (int i = 0; i < 2; ++i) {
        int unit = tid + 256 * i;
        if (unit >= 384) break;
        int c   = unit / 192;
        int rem = unit % 192;
        int pw  = rem >> 3;
        int u   = rem & 7;
        float acc[8];
#pragma unroll
        for (int v = 0; v < 8; ++v) acc[v] = 0.f;
#pragma unroll
        for (int s = 0; s < 8; ++s) {
            int r = (u - s) & 7;
            uint4 q4 = *(const uint4*)&qd[c][s][pw * 8];
            uint4 k4 = *(const uint4*)&krev[c][r][pw * 8];
            u32 Q[4] = {q4.x, q4.y, q4.z, q4.w};
            u32 K[4] = {k4.x, k4.y, k4.z, k4.w};
            u32 S[4];
#pragma unroll
            for (int m = 0; m < 4; ++m) S[m] = (K[m] >> 16) | (K[(m + 1) & 3] << 16);
#pragma unroll
            for (int v = 0; v < 8; ++v) {
                const int o = 8 - v;
#pragma unroll
                for (int tt = 0; tt < 4; ++tt) {
                    u32 pr = (o & 1) ? S[(((o - 1) >> 1) + tt) & 3]
                                     : K[((o >> 1) + tt) & 3];
                    acc[v] = DOT2(Q[tt], pr, acc[v]);
                }
            }
        }
        f16x8 ov;
#pragma unroll
        for (int v = 0; v < 8; ++v) ov[v] = (half_t)acc[v];
        *(f16x8*)&corr[((size_t)lb * 256 + c0 + c) * HW + (size_t)(ph * 8 + u) * WW + pw * 8] = ov;
    }
}

// ---------------------------------------------------------------------------
// Fused LN(corr)*vd + 1x1 proj GEMM via MFMA 32x32x16 -> f32 out. (unchanged)
// ---------------------------------------------------------------------------
__global__ __launch_bounds__(256)
void proj_kernel(const half_t* __restrict__ corr, const half_t* __restrict__ vd,
                 const float* __restrict__ lnw, const float* __restrict__ lnb,
                 const half_t* __restrict__ wp16, const float* __restrict__ wb,
                 float* __restrict__ out)
{
    __shared__ __attribute__((aligned(16))) char smem[SMEM_BYTES];
    half_t (*As)[136]  = (half_t(*)[136])smem;
    half_t (*Wsh)[136] = (half_t(*)[136])(smem + WSH_OFF);
    float  (*Cst)[68]  = (float (*)[68]) (smem + WSH_OFF);
    float* redA = (float*)(smem + WSH_OFF);
    float* redB = (float*)(smem + WSH_OFF + 1024);
    float* mu_s = (float*)(smem + MU_OFF);
    float* rs_s = mu_s + 64;

    const int tid  = threadIdx.x;
    const int px   = tid & 63;
    const int g    = tid >> 6;
    const int l    = tid & 63;
    const int w    = tid >> 6;
    const int lrow = l & 31;
    const int lk   = (l >> 5) * 8;

    const long p0  = (long)blockIdx.x * 64;
    const int  lb  = (int)(p0 / HW);
    const int  hw0 = (int)(p0 - (long)lb * HW);

    const half_t* cb = corr + (size_t)lb * 256 * HW + hw0 + px;
    const half_t* vb = vd   + (size_t)lb * 256 * HW + hw0 + px;

    float s1 = 0.f, s2 = 0.f;
#pragma unroll 8
    for (int j = 0; j < 64; ++j) {
        float cv = (float)cb[(size_t)(g * 64 + j) * HW];
        s1 += cv; s2 += cv * cv;
    }
    redA[g * 64 + px] = s1; redB[g * 64 + px] = s2;
    __syncthreads();
    if (tid < 64) {
        float su = redA[tid] + redA[64 + tid] + redA[128 + tid] + redA[192 + tid];
        float sq = redB[tid] + redB[64 + tid] + redB[128 + tid] + redB[192 + tid];
        float mu  = su * (1.f / 256.f);
        float var = sq * (1.f / 256.f) - mu * mu;
        mu_s[tid] = mu;
        rs_s[tid] = rsqrtf(var + 1e-5f);
    }
    __syncthreads();
    const float mu = mu_s[px], rs = rs_s[px];

    f32x16 acc0, acc1;
#pragma unroll
    for (int i = 0; i < 16; ++i) { acc0[i] = 0.f; acc1[i] = 0.f; }

    for (int kc = 0; kc < 2; ++kc) {
        if (kc) __syncthreads();
#pragma unroll
        for (int m = 0; m < 4; ++m) {
            f16x8 o;
#pragma unroll
            for (int j = 0; j < 8; ++j) {
                int c = kc * 128 + g * 32 + m * 8 + j;
                float cv = (float)cb[(size_t)c * HW];
                float vv = (float)vb[(size_t)c * HW];
                o[j] = (half_t)(((cv - mu) * rs * lnw[c] + lnb[c]) * vv);
            }
            *(f16x8*)&As[px][g * 32 + m * 8] = o;
        }
#pragma unroll
        for (int i = 0; i < 8; ++i) {
            int f  = i * 256 + tid;
            int n  = f >> 4;
            int xh = (f & 15) * 8;
            *(f16x8*)&Wsh[n][xh] = *(const f16x8*)&wp16[(size_t)n * 256 + kc * 128 + xh];
        }
        __syncthreads();

        f16x8 af[8];
#pragma unroll
        for (int kk = 0; kk < 8; ++kk)
            af[kk] = *(const f16x8*)&Wsh[w * 32 + lrow][kk * 16 + lk];
#pragma unroll
        for (int kk = 0; kk < 8; ++kk) {
            f16x8 b0 = *(const f16x8*)&As[lrow][kk * 16 + lk];
            f16x8 b1 = *(const f16x8*)&As[32 + lrow][kk * 16 + lk];
            acc0 = __builtin_amdgcn_mfma_f32_32x32x16_f16(af[kk], b0, acc0, 0, 0, 0);
            acc1 = __builtin_amdgcn_mfma_f32_32x32x16_f16(af[kk], b1, acc1, 0, 0, 0);
        }
    }
    __syncthreads();

#pragma unroll
    for (int r = 0; r < 16; ++r) {
        int oc = w * 32 + (r & 3) + 8 * (r >> 2) + 4 * (l >> 5);
        Cst[oc][lrow]      = acc0[r];
        Cst[oc][32 + lrow] = acc1[r];
    }
    __syncthreads();

#pragma unroll
    for (int i = 0; i < 8; ++i) {
        int idx = i * 256 + tid;
        int oc  = idx >> 4;
        int pxq = idx & 15;
        float4 a = *(const float4*)&Cst[oc][pxq * 4];
        float bias = wb[oc];
        a.x += bias; a.y += bias; a.z += bias; a.w += bias;
        *(float4*)&out[((size_t)lb * 128 + oc) * HW + hw0 + pxq * 4] = a;
    }
}

// ---------------------------------------------------------------------------
extern "C" void kernel_launch(void* const* d_in, const int* in_sizes, int n_in,
                              void* d_out, int out_size, void* d_ws, size_t ws_size,
                              hipStream_t stream)
{
    const float* x        = (const float*)d_in[0];
    const float* evt      = (const float*)d_in[1];
    const float* ln_img_w = (const float*)d_in[2];
    const float* ln_img_b = (const float*)d_in[3];
    const float* ln_evt_w = (const float*)d_in[4];
    const float* ln_evt_b = (const float*)d_in[5];
    const float* q_w      = (const float*)d_in[6];
    const float* q_b      = (const float*)d_in[7];
    const float* q_dw_w   = (const float*)d_in[8];
    const float* q_dw_b   = (const float*)d_in[9];
    const float* kv_w     = (const float*)d_in[10];
    const float* kv_b     = (const float*)d_in[11];
    const float* kv_dw_w  = (const float*)d_in[12];
    const float* kv_dw_b  = (const float*)d_in[13];
    const float* ln_corr_w= (const float*)d_in[14];
    const float* ln_corr_b= (const float*)d_in[15];
    const float* proj_w   = (const float*)d_in[16];
    const float* proj_b   = (const float*)d_in[17];
    float* out = (float*)d_out;

    // f16 weight cache at the tail of ws (137984 halfs = 276 KB)
    const size_t wtail = (ws_size - 278528) & ~(size_t)255;
    half_t* wf    = (half_t*)((char*)d_ws + wtail);
    half_t* wq16  = wf;             // 256x128
    half_t* wkv16 = wf + 32768;     // 512x128
    half_t* wp16  = wf + 98304;     // 128x256
    half_t* qdw16 = wf + 131072;    // 256x9
    half_t* kdw16 = wf + 133376;    // 512x9

    const size_t per_b = (size_t)(256 + 512 + 256 + 256) * HW * sizeof(half_t); // 94.4 MB
    int PB = 1;
    if      (wtail >= 8 * per_b) PB = 8;
    else if (wtail >= 4 * per_b) PB = 4;
    else if (wtail >= 2 * per_b) PB = 2;

    half_t* q1   = (half_t*)d_ws;
    half_t* kv1  = q1  + (size_t)PB * 256 * HW;
    half_t* vd   = kv1 + (size_t)PB * 512 * HW;
    half_t* corr = vd  + (size_t)PB * 256 * HW;

    dim3 blk(256);
    wcvt_kernel<<<135, blk, 0, stream>>>(q_w, kv_w, proj_w, q_dw_w, kv_dw_w, wf);

    for (int b0 = 0; b0 < BATCH; b0 += PB) {
        int nb = PB;
        ln_gemm_kernel<256><<<nb * PXB, blk, 0, stream>>>(
            x + (size_t)b0 * CIN * HW, ln_img_w, ln_img_b, wq16, q_b, q1);
        ln_gemm_kernel<512><<<nb * PXB, blk, 0, stream>>>(
            evt + (size_t)b0 * CIN * HW, ln_evt_w, ln_evt_b, wkv16, kv_b, kv1);
        corr_strip_kernel<<<nb * 24 * 128, blk, 0, stream>>>(
            q1, kv1, qdw16, q_dw_b, kdw16, kv_dw_b, corr, vd);
        proj_kernel<<<nb * PXB, blk, 0, stream>>>(
            corr, vd, ln_corr_w, ln_corr_b, wp16, proj_b,
            out + (size_t)b0 * 128 * HW);
    }
}